// Round 12
// baseline (37.259 us; speedup 1.0000x reference)
//
#include <hip/hip_runtime.h>

#define C_TOT 64
#define Dd 48
#define Hh 128
#define Ww 128
#define HW (Hh*Ww)
#define DHW (Dd*HW)
#define CSPLIT 8            // channels per block
#define CPAD  (CSPLIT + 1)  // bins LDS pad
#define NPL 14              // max unique z-planes per roi window

typedef float f4v __attribute__((ext_vector_type(4), aligned(4)));

__device__ __forceinline__ void axis_interp(float c, int dim, int& lo, int& hi,
                                            float& fr, bool& valid) {
    valid = (c >= -1.0f) && (c <= (float)dim);
    c = fminf(fmaxf(c, 0.0f), (float)(dim - 1));
    float l = floorf(c);
    lo = (int)l;
    hi = min(lo + 1, dim - 1);
    fr = c - l;
}

__device__ __forceinline__ float dot4(f4v v, float w0, float w1, float w2, float w3) {
    return v.x * w0 + v.y * w1 + v.z * w2 + v.w * w3;
}

__global__ __launch_bounds__(1024, 8) void roialign_avg3d_kernel(
    const float* __restrict__ feats, const float* __restrict__ rois,
    float* __restrict__ out)
{
    const int r    = blockIdx.x;   // roi
    const int cb   = blockIdx.y;   // channel octet 0..7
    const int tid  = threadIdx.x;
    const int wv   = tid >> 6;     // phase1: plane index; phase2: z-sample
    const int lane = tid & 63;
    const int xb   = lane & 7;     // x-bin (covers both its x-samples)
    const int ysi  = lane >> 3;    // y-sample sub-index 0..7

    __shared__ float Bst[2][NPL * 16 * 8];     // double-buffered, 14 KB
    __shared__ float bins[16][8][8][CPAD];     // 36.9 KB

    // --- roi params (block-uniform) ---
    const float* rr = rois + r * 7;
    const int   b  = (int)rr[0];
    const float x1 = rr[1] * 0.25f, y1v = rr[2] * 0.25f, z1v = rr[3] * 0.25f;
    const float x2 = rr[4] * 0.25f, y2v = rr[5] * 0.25f, z2v = rr[6] * 0.25f;
    const float rw = fmaxf(x2 - x1, 1.0f);
    const float rh = fmaxf(y2v - y1v, 1.0f);
    const float rd = fmaxf(z2v - z1v, 1.0f);
    const float bsx = rw * 0.125f, bsy = rh * 0.125f, bsz = rd * 0.125f;

    // --- unique z-plane window ---
    const float zc0f = z1v + 0.25f * bsz, zc15f = z1v + 7.75f * bsz;
    const int p0   = (int)floorf(fminf(fmaxf(zc0f, 0.0f), 47.0f));
    const int pphi = min((int)floorf(fminf(fmaxf(zc15f, 0.0f), 47.0f)) + 1, Dd - 1);
    const int pext = pphi - p0 + 1;            // <= 13
    const bool pact = (wv < pext);

    // --- x geometry (lane-fixed): dwordx4 window + folded weights ---
    const float xcA = x1 + (float)xb * bsx + 0.25f * bsx;
    const float xcB = x1 + (float)xb * bsx + 0.75f * bsx;
    int xloA, xhiA, xloB, xhiB; float fxA, fxB; bool vxA, vxB;
    axis_interp(xcA, Ww, xloA, xhiA, fxA, vxA);
    axis_interp(xcB, Ww, xloB, xhiB, fxB, vxB);
    const int base = min(xloA, Ww - 4);
    float w0 = 0.0f, w1 = 0.0f, w2 = 0.0f, w3 = 0.0f;
    {
        const int iA = xloA - base, hA = xhiA - base;
        const int iB = xloB - base, hB = xhiB - base;
        const float a0f = vxA ? (1.0f - fxA) : 0.0f, a1f = vxA ? fxA : 0.0f;
        const float b0f = vxB ? (1.0f - fxB) : 0.0f, b1f = vxB ? fxB : 0.0f;
        w0 += (iA == 0) ? a0f : 0.0f; w1 += (iA == 1) ? a0f : 0.0f; w2 += (iA == 2) ? a0f : 0.0f; w3 += (iA == 3) ? a0f : 0.0f;
        w0 += (hA == 0) ? a1f : 0.0f; w1 += (hA == 1) ? a1f : 0.0f; w2 += (hA == 2) ? a1f : 0.0f; w3 += (hA == 3) ? a1f : 0.0f;
        w0 += (iB == 0) ? b0f : 0.0f; w1 += (iB == 1) ? b0f : 0.0f; w2 += (iB == 2) ? b0f : 0.0f; w3 += (iB == 3) ? b0f : 0.0f;
        w0 += (hB == 0) ? b1f : 0.0f; w1 += (hB == 1) ? b1f : 0.0f; w2 += (hB == 2) ? b1f : 0.0f; w3 += (hB == 3) ? b1f : 0.0f;
    }

    // --- y geometry per half (lane-fixed) ---
    int   o_lo[2], o_hi[2];
    float wyl[2], wyh[2];
    #pragma unroll
    for (int half = 0; half < 2; ++half) {
        const int ys = half * 8 + ysi;
        const float yc = y1v + (float)(ys >> 1) * bsy + ((float)(ys & 1) + 0.5f) * 0.5f * bsy;
        int ylo, yhi; float fy; bool vy;
        axis_interp(yc, Hh, ylo, yhi, fy, vy);
        wyl[half] = vy ? (1.0f - fy) : 0.0f;
        wyh[half] = vy ? fy : 0.0f;
        o_lo[half] = ylo * Ww + base;
        o_hi[half] = yhi * Ww + base;
    }

    // --- phase-2 z interp (wave-fixed) ---
    const float zc = z1v + (float)(wv >> 1) * bsz + ((float)(wv & 1) + 0.5f) * 0.5f * bsz;
    int zlo, zhi; float fz; bool vz;
    axis_interp(zc, Dd, zlo, zhi, fz, vz);
    const float wz0 = vz ? (1.0f - fz) : 0.0f;
    const float wz1 = vz ? fz : 0.0f;
    const int   a0  = (zlo - p0) * 128 + lane;
    const int   a1  = (zhi - p0) * 128 + lane;

    const float* fb = feats + (size_t)(b * C_TOT + cb * CSPLIT) * (size_t)DHW;
    const float* pp = fb + (size_t)(p0 + wv) * HW;   // my plane, channel 0

    // --- prefetch channel 0 into reg set 0 ---
    f4v R[2][4] = {};
    if (pact) {
        R[0][0] = *(const f4v*)(pp + o_lo[0]);
        R[0][1] = *(const f4v*)(pp + o_hi[0]);
        R[0][2] = *(const f4v*)(pp + o_lo[1]);
        R[0][3] = *(const f4v*)(pp + o_hi[1]);
    }

    const bool writer = !(ysi & 1);
    const int  ybl    = ysi >> 1;

    #pragma unroll
    for (int c = 0; c < CSPLIT; ++c) {
        const int cur = c & 1, nxt = cur ^ 1;
        // issue channel c+1 loads FIRST (flight spans compute+write+barrier+phase2)
        if (c + 1 < CSPLIT) {
            pp += DHW;
            if (pact) {
                R[nxt][0] = *(const f4v*)(pp + o_lo[0]);
                R[nxt][1] = *(const f4v*)(pp + o_hi[0]);
                R[nxt][2] = *(const f4v*)(pp + o_lo[1]);
                R[nxt][3] = *(const f4v*)(pp + o_hi[1]);
            }
        }
        // phase 1: xy-bilinear, x-pair-folded, one unique plane per wave
        if (pact) {
            const float B0 = wyl[0] * dot4(R[cur][0], w0, w1, w2, w3)
                           + wyh[0] * dot4(R[cur][1], w0, w1, w2, w3);
            const float B1 = wyl[1] * dot4(R[cur][2], w0, w1, w2, w3)
                           + wyh[1] * dot4(R[cur][3], w0, w1, w2, w3);
            Bst[cur][wv * 128 +      lane] = B0;
            Bst[cur][wv * 128 + 64 + lane] = B1;
        }
        __syncthreads();   // single barrier: Bst[cur] visible; prev reads of this
                           // buffer were fenced by barrier(c-1)

        // phase 2: z-combine (wave-uniform plane rows, stride-1 conflict-free)
        #pragma unroll
        for (int yy = 0; yy < 2; ++yy) {
            float v = wz0 * Bst[cur][a0 + yy * 64] + wz1 * Bst[cur][a1 + yy * 64];
            v += __shfl_xor(v, 8);            // reduce y-sample pair
            if (writer)
                bins[wv][yy * 4 + ybl][xb][c] = v;
        }
    }
    __syncthreads();

    // --- fused pooling: out(dz,h,w) = (1/64) * sum over 4 z-slices, 2 yb, 2 xb ---
    for (int i = tid; i < CSPLIT * 7 * 7 * 7; i += 1024) {
        const int w  = i % 7;
        const int h  = (i / 7) % 7;
        const int dz = (i / 49) % 7;
        const int c  = i / 343;
        float acc = 0.0f;
        #pragma unroll
        for (int g = 0; g < 4; ++g) {
            const int z = 2 * dz + g;
            acc += bins[z][h    ][w][c] + bins[z][h    ][w + 1][c]
                 + bins[z][h + 1][w][c] + bins[z][h + 1][w + 1][c];
        }
        acc *= (1.0f / 64.0f);
        const int cg = cb * CSPLIT + c;
        out[((((size_t)r * C_TOT + cg) * 7 + dz) * 7 + h) * 7 + w] = acc;
    }
}

extern "C" void kernel_launch(void* const* d_in, const int* in_sizes, int n_in,
                              void* d_out, int out_size, void* d_ws, size_t ws_size,
                              hipStream_t stream) {
    const float* feats = (const float*)d_in[0];
    const float* rois  = (const float*)d_in[1];
    float* out = (float*)d_out;
    const int R = in_sizes[1] / 7;   // 64
    dim3 grid(R, C_TOT / CSPLIT);
    roialign_avg3d_kernel<<<grid, 1024, 0, stream>>>(feats, rois, out);
}

// Round 13
// 32.153 us; speedup vs baseline: 1.1588x; 1.1588x over previous
//
#include <hip/hip_runtime.h>

#define C_TOT 64
#define Dd 48
#define Hh 128
#define Ww 128
#define HW (Hh*Ww)
#define DHW (Dd*HW)
#define CSPLIT 8            // channels per block
#define CPAD  (CSPLIT + 1)  // bins LDS pad
#define NPL 14              // max unique z-planes per roi window

typedef float f4v __attribute__((ext_vector_type(4), aligned(4)));

__device__ __forceinline__ void axis_interp(float c, int dim, int& lo, int& hi,
                                            float& fr, bool& valid) {
    valid = (c >= -1.0f) && (c <= (float)dim);
    c = fminf(fmaxf(c, 0.0f), (float)(dim - 1));
    float l = floorf(c);
    lo = (int)l;
    hi = min(lo + 1, dim - 1);
    fr = c - l;
}

__device__ __forceinline__ float dot4(f4v v, float w0, float w1, float w2, float w3) {
    return v.x * w0 + v.y * w1 + v.z * w2 + v.w * w3;
}

// Barrier that orders LDS only: does NOT drain vmcnt, so global prefetch
// loads stay in flight across it (compiler inserts the counted vmcnt wait
// at the loads' first use). __syncthreads would force vmcnt(0) here.
__device__ __forceinline__ void lds_barrier() {
    asm volatile("s_waitcnt lgkmcnt(0)" ::: "memory");
    __builtin_amdgcn_s_barrier();
}

__global__ __launch_bounds__(1024, 8) void roialign_avg3d_kernel(
    const float* __restrict__ feats, const float* __restrict__ rois,
    float* __restrict__ out)
{
    const int r    = blockIdx.x;   // roi
    const int cb   = blockIdx.y;   // channel octet 0..7
    const int tid  = threadIdx.x;
    const int wv   = tid >> 6;     // phase1: plane index; phase2: z-sample
    const int lane = tid & 63;
    const int xb   = lane & 7;     // x-bin (covers both its x-samples)
    const int ysi  = lane >> 3;    // y-sample sub-index 0..7

    __shared__ float Bst[NPL * 16 * 8];        // [p][ys][xb] bilinear partials, 7 KB
    __shared__ float bins[16][8][8][CPAD];     // 36.9 KB

    // --- roi params (block-uniform) ---
    const float* rr = rois + r * 7;
    const int   b  = (int)rr[0];
    const float x1 = rr[1] * 0.25f, y1v = rr[2] * 0.25f, z1v = rr[3] * 0.25f;
    const float x2 = rr[4] * 0.25f, y2v = rr[5] * 0.25f, z2v = rr[6] * 0.25f;
    const float rw = fmaxf(x2 - x1, 1.0f);
    const float rh = fmaxf(y2v - y1v, 1.0f);
    const float rd = fmaxf(z2v - z1v, 1.0f);
    const float bsx = rw * 0.125f, bsy = rh * 0.125f, bsz = rd * 0.125f;

    // --- unique z-plane window ---
    const float zc0f = z1v + 0.25f * bsz, zc15f = z1v + 7.75f * bsz;
    const int p0   = (int)floorf(fminf(fmaxf(zc0f, 0.0f), 47.0f));
    const int pphi = min((int)floorf(fminf(fmaxf(zc15f, 0.0f), 47.0f)) + 1, Dd - 1);
    const int pext = pphi - p0 + 1;            // <= 13
    const bool pact = (wv < pext);

    // --- x geometry (lane-fixed): dwordx4 window + folded weights ---
    const float xcA = x1 + (float)xb * bsx + 0.25f * bsx;
    const float xcB = x1 + (float)xb * bsx + 0.75f * bsx;
    int xloA, xhiA, xloB, xhiB; float fxA, fxB; bool vxA, vxB;
    axis_interp(xcA, Ww, xloA, xhiA, fxA, vxA);
    axis_interp(xcB, Ww, xloB, xhiB, fxB, vxB);
    const int base = min(xloA, Ww - 4);
    float w0 = 0.0f, w1 = 0.0f, w2 = 0.0f, w3 = 0.0f;
    {
        const int iA = xloA - base, hA = xhiA - base;
        const int iB = xloB - base, hB = xhiB - base;
        const float a0 = vxA ? (1.0f - fxA) : 0.0f, a1 = vxA ? fxA : 0.0f;
        const float b0 = vxB ? (1.0f - fxB) : 0.0f, b1 = vxB ? fxB : 0.0f;
        w0 += (iA == 0) ? a0 : 0.0f; w1 += (iA == 1) ? a0 : 0.0f; w2 += (iA == 2) ? a0 : 0.0f; w3 += (iA == 3) ? a0 : 0.0f;
        w0 += (hA == 0) ? a1 : 0.0f; w1 += (hA == 1) ? a1 : 0.0f; w2 += (hA == 2) ? a1 : 0.0f; w3 += (hA == 3) ? a1 : 0.0f;
        w0 += (iB == 0) ? b0 : 0.0f; w1 += (iB == 1) ? b0 : 0.0f; w2 += (iB == 2) ? b0 : 0.0f; w3 += (iB == 3) ? b0 : 0.0f;
        w0 += (hB == 0) ? b1 : 0.0f; w1 += (hB == 1) ? b1 : 0.0f; w2 += (hB == 2) ? b1 : 0.0f; w3 += (hB == 3) ? b1 : 0.0f;
    }

    // --- y geometry per half (lane-fixed) ---
    int   o_lo[2], o_hi[2];
    float wyl[2], wyh[2];
    #pragma unroll
    for (int half = 0; half < 2; ++half) {
        const int ys = half * 8 + ysi;
        const float yc = y1v + (float)(ys >> 1) * bsy + ((float)(ys & 1) + 0.5f) * 0.5f * bsy;
        int ylo, yhi; float fy; bool vy;
        axis_interp(yc, Hh, ylo, yhi, fy, vy);
        wyl[half] = vy ? (1.0f - fy) : 0.0f;
        wyh[half] = vy ? fy : 0.0f;
        o_lo[half] = ylo * Ww + base;
        o_hi[half] = yhi * Ww + base;
    }

    // --- phase-2 z interp (wave-fixed) ---
    const float zc = z1v + (float)(wv >> 1) * bsz + ((float)(wv & 1) + 0.5f) * 0.5f * bsz;
    int zlo, zhi; float fz; bool vz;
    axis_interp(zc, Dd, zlo, zhi, fz, vz);
    const float wz0 = vz ? (1.0f - fz) : 0.0f;
    const float wz1 = vz ? fz : 0.0f;
    const int   a0  = (zlo - p0) * 128 + lane;   // Bst flat: p*128 + yy*64 + lane
    const int   a1  = (zhi - p0) * 128 + lane;

    const float* fb = feats + (size_t)(b * C_TOT + cb * CSPLIT) * (size_t)DHW;
    const float* pp = fb + (size_t)(p0 + wv) * HW;   // my plane, channel 0

    // --- prefetch channel 0 rows ---
    f4v R0 = {0,0,0,0}, R1 = {0,0,0,0}, R2 = {0,0,0,0}, R3 = {0,0,0,0};
    if (pact) {
        R0 = *(const f4v*)(pp + o_lo[0]);
        R1 = *(const f4v*)(pp + o_hi[0]);
        R2 = *(const f4v*)(pp + o_lo[1]);
        R3 = *(const f4v*)(pp + o_hi[1]);
    }

    const bool writer = !(ysi & 1);
    const int  ybl    = ysi >> 1;

    for (int c = 0; c < CSPLIT; ++c) {
        // --- phase 1 compute: xy-bilinear, x-pair-folded, per unique plane ---
        float B0 = 0.0f, B1 = 0.0f;
        if (pact) {
            B0 = wyl[0] * dot4(R0, w0, w1, w2, w3) + wyh[0] * dot4(R1, w0, w1, w2, w3);
            B1 = wyl[1] * dot4(R2, w0, w1, w2, w3) + wyh[1] * dot4(R3, w0, w1, w2, w3);
        }
        // prefetch channel c+1 — with lds_barrier (no vmcnt drain) these loads
        // fly across BOTH barriers + phase 2 and complete at next iter's use
        if (c + 1 < CSPLIT) {
            pp += DHW;
            if (pact) {
                R0 = *(const f4v*)(pp + o_lo[0]);
                R1 = *(const f4v*)(pp + o_hi[0]);
                R2 = *(const f4v*)(pp + o_lo[1]);
                R3 = *(const f4v*)(pp + o_hi[1]);
            }
        }
        lds_barrier();     // Bst(c-1) fully consumed by phase 2 of prev iter
        if (pact) {
            Bst[wv * 128 +      lane] = B0;   // [p][ys=ysi  ][xb] — stride-1
            Bst[wv * 128 + 64 + lane] = B1;   // [p][ys=8+ysi][xb]
        }
        lds_barrier();     // Bst(c) visible

        // --- phase 2: z-combine two plane slices (wave-uniform, stride-1) ---
        #pragma unroll
        for (int yy = 0; yy < 2; ++yy) {
            float v = wz0 * Bst[a0 + yy * 64] + wz1 * Bst[a1 + yy * 64];
            v += __shfl_xor(v, 8);            // reduce y-sample pair
            if (writer)
                bins[wv][yy * 4 + ybl][xb][c] = v;
        }
    }
    __syncthreads();

    // --- fused pooling: out(dz,h,w) = (1/64) * sum over 4 z-slices, 2 yb, 2 xb ---
    for (int i = tid; i < CSPLIT * 7 * 7 * 7; i += 1024) {
        const int w  = i % 7;
        const int h  = (i / 7) % 7;
        const int dz = (i / 49) % 7;
        const int c  = i / 343;
        float acc = 0.0f;
        #pragma unroll
        for (int g = 0; g < 4; ++g) {
            const int z = 2 * dz + g;
            acc += bins[z][h    ][w][c] + bins[z][h    ][w + 1][c]
                 + bins[z][h + 1][w][c] + bins[z][h + 1][w + 1][c];
        }
        acc *= (1.0f / 64.0f);
        const int cg = cb * CSPLIT + c;
        out[((((size_t)r * C_TOT + cg) * 7 + dz) * 7 + h) * 7 + w] = acc;
    }
}

extern "C" void kernel_launch(void* const* d_in, const int* in_sizes, int n_in,
                              void* d_out, int out_size, void* d_ws, size_t ws_size,
                              hipStream_t stream) {
    const float* feats = (const float*)d_in[0];
    const float* rois  = (const float*)d_in[1];
    float* out = (float*)d_out;
    const int R = in_sizes[1] / 7;   // 64
    dim3 grid(R, C_TOT / CSPLIT);
    roialign_avg3d_kernel<<<grid, 1024, 0, stream>>>(feats, rois, out);
}